// Round 3
// baseline (280.861 us; speedup 1.0000x reference)
//
#include <hip/hip_runtime.h>
#include <stdint.h>

#define B_DIM 8192
#define H_DIM 1024
#define E_DIM 300
#define A_DIM 512
#define KP    1920   // 1024 + 320(pad 300) + 512 + 64 zero-pad = 60*32
#define KE0   1024
#define KA0   1344
#define KA1   1856
#define BK    32
#define NT    60     // K tiles of 32

typedef __bf16 bf16;
typedef bf16  bf16x8 __attribute__((ext_vector_type(8)));
typedef float f32x4  __attribute__((ext_vector_type(4)));

__device__ __forceinline__ uint16_t f2bf(float f) {
  uint32_t u = __float_as_uint(f);
  u += 0x7fff + ((u >> 16) & 1);   // round-to-nearest-even
  return (uint16_t)(u >> 16);
}

// ---- pack X = [B][KP] bf16 : [h | emb | pad | ctx | pad] ----
__global__ void pack_x_kernel(const float* __restrict__ h,
                              const float* __restrict__ e,
                              const float* __restrict__ a,
                              uint16_t* __restrict__ X) {
  int idx = blockIdx.x * blockDim.x + threadIdx.x;
  const int gpr = KP / 8;
  if (idx >= B_DIM * gpr) return;
  int row  = idx / gpr;
  int col0 = (idx % gpr) * 8;
  __align__(16) uint16_t v[8];
#pragma unroll
  for (int j = 0; j < 8; ++j) {
    int c = col0 + j;
    float x;
    if (c < KE0) x = h[(size_t)row * H_DIM + c];
    else if (c < KA0) {
      int ce = c - KE0;
      x = (ce < E_DIM) ? e[(size_t)row * E_DIM + ce] : 0.f;
    } else if (c < KA1) x = a[(size_t)row * A_DIM + (c - KA0)];
    else x = 0.f;
    v[j] = f2bf(x);
  }
  *(uint4*)(X + (size_t)row * KP + col0) = *(const uint4*)v;
}

// ---- pack W = [4096][KP] bf16, gate-interleaved at 64-unit granularity ----
__global__ void pack_w_kernel(const float* __restrict__ Wh,
                              const float* __restrict__ Wx,
                              const float* __restrict__ Wa,
                              uint16_t* __restrict__ W) {
  int idx = blockIdx.x * blockDim.x + threadIdx.x;
  const int gpr = KP / 8;
  if (idx >= 4096 * gpr) return;
  int pr   = idx / gpr;
  int col0 = (idx % gpr) * 8;
  int ub = pr >> 8, g = (pr >> 6) & 3, ui = pr & 63;
  size_t srow = (size_t)(g * H_DIM + ub * 64 + ui);
  __align__(16) uint16_t v[8];
#pragma unroll
  for (int j = 0; j < 8; ++j) {
    int c = col0 + j;
    float x;
    if (c < KE0) x = Wh[srow * H_DIM + c];
    else if (c < KA0) {
      int ce = c - KE0;
      x = (ce < E_DIM) ? Wx[srow * E_DIM + ce] : 0.f;
    } else if (c < KA1) x = Wa[srow * A_DIM + (c - KA0)];
    else x = 0.f;
    v[j] = f2bf(x);
  }
  *(uint4*)(W + (size_t)pr * KP + col0) = *(const uint4*)v;
}

__device__ __forceinline__ void async_copy16(const void* g, void* l) {
  __builtin_amdgcn_global_load_lds(
      (__attribute__((address_space(1))) void*)g,
      (__attribute__((address_space(3))) void*)l, 16, 0, 0);
}

__device__ __forceinline__ float fast_tanh(float x) {
  float ax = fabsf(x);
  float e  = __expf(2.f * ax);
  float r  = 1.f - 2.f / (e + 1.f);   // large ax: e->inf -> r->1 (graceful)
  return copysignf(r, x);
}

#define WAITN(n) asm volatile("s_waitcnt vmcnt(" #n ")" ::: "memory")
#define SB0 __builtin_amdgcn_sched_barrier(0)

// One K-tile group: stage tile KT+2 into buf FILL, read frags from buf CONS,
// 32 MFMA (unpinned: compiler interleaves ds_read/MFMA via lgkmcnt), counted
// vmcnt wait, ONE barrier. SB0 after barrier stops load-hoisting (rule 18/19).
// WAR safe: FILL's last readers finished before this group's opening barrier.
// RAW safe: CONS was staged in group T-2; every wave drains its own slice at
// the end of group T-1 (wait precedes barrier), so barrier publishes all.
#define GROUP(CONS, FILL, KT, DOSTAGE, WCODE)                                                \
  {                                                                                          \
    if (DOSTAGE) {                                                                           \
      stA(KT + 2, 0, FILL); stA(KT + 2, 1, FILL);                                            \
      stB(KT + 2, 0, FILL); stB(KT + 2, 1, FILL);                                            \
    }                                                                                        \
    const uint16_t* Ab = Abase + (CONS) * 16384;                                             \
    const uint16_t* Bb = Bbase + (CONS) * 16384;                                             \
    bf16x8 bf[4], af[8];                                                                     \
    _Pragma("unroll") for (int n_ = 0; n_ < 4; ++n_)                                         \
      bf[n_] = *(const bf16x8*)(Bb + n_ * 512);                                              \
    _Pragma("unroll") for (int m_ = 0; m_ < 8; ++m_)                                         \
      af[m_] = *(const bf16x8*)(Ab + m_ * 512);                                              \
    _Pragma("unroll") for (int m_ = 0; m_ < 8; ++m_)                                         \
      _Pragma("unroll") for (int n_ = 0; n_ < 4; ++n_)                                       \
        acc[m_][n_] = __builtin_amdgcn_mfma_f32_16x16x32_bf16(af[m_], bf[n_], acc[m_][n_], 0, 0, 0); \
    WCODE;                                                                                   \
    __builtin_amdgcn_s_barrier();                                                            \
    SB0;                                                                                     \
  }

// ---- fused GEMM + gates: 256x256 tile, 8 waves (2Mx4N), BK=32,
//      3-buffer LDS rotation, 1 barrier + 1 counted vmcnt per K-tile. ----
__global__ __launch_bounds__(512, 2) void lstm_fused_kernel(
    const uint16_t* __restrict__ X, const uint16_t* __restrict__ W,
    const float* __restrict__ c_prev,
    const float* __restrict__ b0, const float* __restrict__ b1,
    const float* __restrict__ b2, const float* __restrict__ b3,
    float* __restrict__ out) {
  __shared__ __align__(16) uint16_t smem[3 * 16384];  // 96 KiB: 3 x (A16K|B16K)

  const int t    = threadIdx.x;
  const int lane = t & 63;
  const int wid  = t >> 6;
  const int wr   = wid >> 2;            // 0..1 : row half (128 rows each)
  const int wc   = wid & 3;             // 0..3 : gate / 64-col block
  const int lr   = lane & 15;
  const int kh   = lane >> 4;
  const int m0   = blockIdx.x * 256;
  const int by   = blockIdx.y;
  const int n0   = by * 256;            // packed-W row base

  // bias folded into accumulator init
  f32x4 acc[8][4];
#pragma unroll
  for (int n = 0; n < 4; ++n) {
    int bidx = wc * H_DIM + by * 64 + n * 16 + lr;
    float bs = b0[bidx] + b1[bidx] + b2[bidx] + b3[bidx];
#pragma unroll
    for (int m = 0; m < 8; ++m) acc[m][n] = (f32x4){bs, bs, bs, bs};
  }

  // staging: one call = 512 thr x 16B = 8 KB = 128 rows x 32 elems (64B/row).
  // Linear LDS dest (base + t*16B); global source chunk pre-XOR'd by row&3.
  const int sr   = t >> 2;                          // row 0..127 within call
  const int csrc = (((t & 3) ^ (sr & 3)) * 8);      // pre-swizzled source chunk

  auto stA = [&](int kt_, int hf_, int buf_) {
    async_copy16(X + (size_t)(m0 + hf_ * 128 + sr) * KP + kt_ * BK + csrc,
                 smem + buf_ * 16384 + hf_ * 4096 + t * 8);
  };
  auto stB = [&](int kt_, int hf_, int buf_) {
    async_copy16(W + (size_t)(n0 + hf_ * 128 + sr) * KP + kt_ * BK + csrc,
                 smem + buf_ * 16384 + 8192 + hf_ * 4096 + t * 8);
  };

  // frag read bases: row r, global chunk kh lives at LDS chunk kh ^ (r&3);
  // r&3 == lr&3 for all frags -> lane-constant. Wave covers 16 rows x 64B
  // contiguous per b128 -> conflict-free.
  const int ckr = (kh ^ (lr & 3)) * 8;
  const uint16_t* Abase = smem + (wr * 128 + lr) * 32 + ckr;
  const uint16_t* Bbase = smem + 8192 + (wc * 64 + lr) * 32 + ckr;

  // prologue: tile0 -> buf0, tile1 -> buf1; drain tile0 (4 newest = tile1 stay)
  stA(0, 0, 0); stA(0, 1, 0); stB(0, 0, 0); stB(0, 1, 0);
  stA(1, 0, 1); stA(1, 1, 1); stB(1, 0, 1); stB(1, 1, 1);
  WAITN(4);
  __builtin_amdgcn_s_barrier();
  SB0;

  // groups 0..56 (19 triples), then 57 (last stage), 58 (drain), 59
#pragma unroll 1
  for (int it = 0; it < 19; ++it) {
    const int kt = it * 3;
    GROUP(0, 2, kt,     true, WAITN(4))
    GROUP(1, 0, kt + 1, true, WAITN(4))
    GROUP(2, 1, kt + 2, true, WAITN(4))
  }
  GROUP(0, 2, 57, true,  WAITN(4))
  GROUP(1, 0, 58, false, WAITN(0))
  GROUP(2, 1, 59, false, (void)0)

  // ---- fused epilogue: 4 rounds of 64 rows through pre[64][256] (64 KiB,
  //      bufs 0/1 only -> disjoint from group 59's buf2).
  //      col XOR'd by writer's kh<<4 -> 2-way (free) aliasing both sides. ----
  float* pre  = (float*)smem;
  float* outh = out;
  float* outc = out + (size_t)B_DIM * H_DIM;
  const int eu = lane;
#pragma unroll 1
  for (int ph = 0; ph < 4; ++ph) {
    if (wr == (ph >> 1)) {
      const int mb = (ph & 1) * 4;
#pragma unroll
      for (int mi = 0; mi < 4; ++mi)
#pragma unroll
        for (int n = 0; n < 4; ++n) {
          int rr  = mi * 16 + kh * 4;
          int col = wc * 64 + ((n ^ kh) << 4) + lr;
#pragma unroll
          for (int j = 0; j < 4; ++j)
            pre[(rr + j) * 256 + col] = acc[mb + mi][n][j];
        }
    }
    __syncthreads();
#pragma unroll 1
    for (int q = 0; q < 8; ++q) {
      int rr  = wid * 8 + q;
      int ec  = eu ^ ((rr & 12) << 2);
      float pi = pre[rr * 256 + ec];
      float pf = pre[rr * 256 + 64 + ec];
      float po = pre[rr * 256 + 128 + ec];
      float pg = pre[rr * 256 + 192 + ec];
      size_t o = (size_t)(m0 + ph * 64 + rr) * H_DIM + by * 64 + eu;
      float cp = c_prev[o];
      float iv = 1.f / (1.f + __expf(-pi));
      float fv = 1.f / (1.f + __expf(-pf));
      float ov = 1.f / (1.f + __expf(-po));
      float gv = fast_tanh(pg);
      float ct = fv * cp + iv * gv;
      float ht = ov * fast_tanh(ct);
      outh[o] = ht;
      outc[o] = ct;
    }
    __syncthreads();
  }
}

extern "C" void kernel_launch(void* const* d_in, const int* in_sizes, int n_in,
                              void* d_out, int out_size, void* d_ws, size_t ws_size,
                              hipStream_t stream) {
  const float* h_prev = (const float*)d_in[0];
  const float* c_prev = (const float*)d_in[1];
  const float* emb    = (const float*)d_in[2];
  const float* ctx    = (const float*)d_in[3];
  const float* Wh     = (const float*)d_in[4];
  const float* Wx     = (const float*)d_in[5];
  const float* Wa     = (const float*)d_in[6];
  const float* bl     = (const float*)d_in[7];
  const float* bl2    = (const float*)d_in[8];
  const float* bl3    = (const float*)d_in[9];
  const float* bp     = (const float*)d_in[10];

  uint16_t* X = (uint16_t*)d_ws;                                   // 31.5 MB
  uint16_t* W = (uint16_t*)((char*)d_ws + (size_t)B_DIM * KP * 2); // 15.7 MB
  float* out = (float*)d_out;

  {
    int total = B_DIM * (KP / 8);
    pack_x_kernel<<<(total + 255) / 256, 256, 0, stream>>>(h_prev, emb, ctx, X);
  }
  {
    int total = 4096 * (KP / 8);
    pack_w_kernel<<<(total + 255) / 256, 256, 0, stream>>>(Wh, Wx, Wa, W);
  }
  dim3 grid(B_DIM / 256, 4096 / 256);   // (32, 16)
  lstm_fused_kernel<<<grid, 512, 0, stream>>>(X, W, c_prev, bl, bl2, bl3, bp, out);
}

// Round 4
// 263.596 us; speedup vs baseline: 1.0655x; 1.0655x over previous
//
#include <hip/hip_runtime.h>
#include <stdint.h>

#define B_DIM 8192
#define H_DIM 1024
#define E_DIM 300
#define A_DIM 512
#define KP    1920   // 1024 + 320(pad 300) + 512 + 64 zero-pad = 60*32
#define KE0   1024
#define KA0   1344
#define KA1   1856
#define BK    32
#define NT    60     // K tiles of 32

typedef __bf16 bf16;
typedef bf16  bf16x8 __attribute__((ext_vector_type(8)));
typedef float f32x4  __attribute__((ext_vector_type(4)));

__device__ __forceinline__ uint16_t f2bf(float f) {
  uint32_t u = __float_as_uint(f);
  u += 0x7fff + ((u >> 16) & 1);   // round-to-nearest-even
  return (uint16_t)(u >> 16);
}

// ---- pack X = [B][KP] bf16 : [h | emb | pad | ctx | pad] ----
__global__ void pack_x_kernel(const float* __restrict__ h,
                              const float* __restrict__ e,
                              const float* __restrict__ a,
                              uint16_t* __restrict__ X) {
  int idx = blockIdx.x * blockDim.x + threadIdx.x;
  const int gpr = KP / 8;
  if (idx >= B_DIM * gpr) return;
  int row  = idx / gpr;
  int col0 = (idx % gpr) * 8;
  __align__(16) uint16_t v[8];
#pragma unroll
  for (int j = 0; j < 8; ++j) {
    int c = col0 + j;
    float x;
    if (c < KE0) x = h[(size_t)row * H_DIM + c];
    else if (c < KA0) {
      int ce = c - KE0;
      x = (ce < E_DIM) ? e[(size_t)row * E_DIM + ce] : 0.f;
    } else if (c < KA1) x = a[(size_t)row * A_DIM + (c - KA0)];
    else x = 0.f;
    v[j] = f2bf(x);
  }
  *(uint4*)(X + (size_t)row * KP + col0) = *(const uint4*)v;
}

// ---- pack W = [4096][KP] bf16, gate-interleaved at 64-unit granularity ----
__global__ void pack_w_kernel(const float* __restrict__ Wh,
                              const float* __restrict__ Wx,
                              const float* __restrict__ Wa,
                              uint16_t* __restrict__ W) {
  int idx = blockIdx.x * blockDim.x + threadIdx.x;
  const int gpr = KP / 8;
  if (idx >= 4096 * gpr) return;
  int pr   = idx / gpr;
  int col0 = (idx % gpr) * 8;
  int ub = pr >> 8, g = (pr >> 6) & 3, ui = pr & 63;
  size_t srow = (size_t)(g * H_DIM + ub * 64 + ui);
  __align__(16) uint16_t v[8];
#pragma unroll
  for (int j = 0; j < 8; ++j) {
    int c = col0 + j;
    float x;
    if (c < KE0) x = Wh[srow * H_DIM + c];
    else if (c < KA0) {
      int ce = c - KE0;
      x = (ce < E_DIM) ? Wx[srow * E_DIM + ce] : 0.f;
    } else if (c < KA1) x = Wa[srow * A_DIM + (c - KA0)];
    else x = 0.f;
    v[j] = f2bf(x);
  }
  *(uint4*)(W + (size_t)pr * KP + col0) = *(const uint4*)v;
}

__device__ __forceinline__ void async_copy16(const void* g, void* l) {
  __builtin_amdgcn_global_load_lds(
      (__attribute__((address_space(1))) void*)g,
      (__attribute__((address_space(3))) void*)l, 16, 0, 0);
}

__device__ __forceinline__ float fast_tanh(float x) {
  float ax = fabsf(x);
  float e  = __expf(2.f * ax);
  float r  = 1.f - 2.f / (e + 1.f);
  return copysignf(r, x);
}

#define WAITN(n) asm volatile("s_waitcnt vmcnt(" #n ")" ::: "memory")
#define SB0 __builtin_amdgcn_sched_barrier(0)

#define MF(M, AV)                                                                        \
    acc[M][0] = __builtin_amdgcn_mfma_f32_16x16x32_bf16(AV, b0, acc[M][0], 0, 0, 0);     \
    acc[M][1] = __builtin_amdgcn_mfma_f32_16x16x32_bf16(AV, b1, acc[M][1], 0, 0, 0);     \
    acc[M][2] = __builtin_amdgcn_mfma_f32_16x16x32_bf16(AV, b2, acc[M][2], 0, 0, 0);     \
    acc[M][3] = __builtin_amdgcn_mfma_f32_16x16x32_bf16(AV, b3, acc[M][3], 0, 0, 0);

// One K-tile group: stage tile KT+2 into buf FILL, read frags from buf CONS
// (two 4-frag halves -> peak live regs ~ acc128+48, no spill), 32 MFMA,
// counted vmcnt, ONE barrier. SB0 after barrier stops load-hoisting only.
// WAR: FILL's readers finished before the barrier that opened this group.
// RAW: CONS staged 2 groups ago; WAITN(4) at end of prev group drained it,
// barrier published it.
#define GROUP(CONS, FILL, KT, DOSTAGE, WCODE)                                            \
  {                                                                                      \
    if (DOSTAGE) {                                                                       \
      stA(KT + 2, 0, FILL); stA(KT + 2, 1, FILL);                                        \
      stB(KT + 2, 0, FILL); stB(KT + 2, 1, FILL);                                        \
    }                                                                                    \
    const uint16_t* Ab = Abase + (CONS) * 16384;                                         \
    const uint16_t* Bb = Bbase + (CONS) * 16384;                                         \
    bf16x8 b0 = *(const bf16x8*)(Bb);                                                    \
    bf16x8 b1 = *(const bf16x8*)(Bb + 512);                                              \
    bf16x8 b2 = *(const bf16x8*)(Bb + 1024);                                             \
    bf16x8 b3 = *(const bf16x8*)(Bb + 1536);                                             \
    {                                                                                    \
      bf16x8 a0 = *(const bf16x8*)(Ab);                                                  \
      bf16x8 a1 = *(const bf16x8*)(Ab + 512);                                            \
      bf16x8 a2 = *(const bf16x8*)(Ab + 1024);                                           \
      bf16x8 a3 = *(const bf16x8*)(Ab + 1536);                                           \
      MF(0, a0) MF(1, a1) MF(2, a2) MF(3, a3)                                            \
    }                                                                                    \
    {                                                                                    \
      bf16x8 a4 = *(const bf16x8*)(Ab + 2048);                                           \
      bf16x8 a5 = *(const bf16x8*)(Ab + 2560);                                           \
      bf16x8 a6 = *(const bf16x8*)(Ab + 3072);                                           \
      bf16x8 a7 = *(const bf16x8*)(Ab + 3584);                                           \
      MF(4, a4) MF(5, a5) MF(6, a6) MF(7, a7)                                            \
    }                                                                                    \
    WCODE;                                                                               \
    __builtin_amdgcn_s_barrier();                                                        \
    SB0;                                                                                 \
  }

// ---- fused GEMM + gates: 256x256 tile, 8 waves (2Mx4N), BK=32,
//      3-buffer LDS rotation, 1 barrier + 1 counted vmcnt per K-tile. ----
__global__ __launch_bounds__(512, 2) void lstm_fused_kernel(
    const uint16_t* __restrict__ X, const uint16_t* __restrict__ W,
    const float* __restrict__ c_prev,
    const float* __restrict__ b0_, const float* __restrict__ b1_,
    const float* __restrict__ b2_, const float* __restrict__ b3_,
    float* __restrict__ out) {
  __shared__ __align__(16) uint16_t smem[3 * 16384];  // 96 KiB: 3 x (A16K|B16K)

  const int t    = threadIdx.x;
  const int lane = t & 63;
  const int wid  = t >> 6;
  const int wr   = wid >> 2;            // 0..1 : row half (128 rows each)
  const int wc   = wid & 3;             // 0..3 : gate / 64-col block
  const int lr   = lane & 15;
  const int kh   = lane >> 4;
  const int m0   = blockIdx.x * 256;
  const int by   = blockIdx.y;
  const int n0   = by * 256;            // packed-W row base

  // bias folded into accumulator init
  f32x4 acc[8][4];
#pragma unroll
  for (int n = 0; n < 4; ++n) {
    int bidx = wc * H_DIM + by * 64 + n * 16 + lr;
    float bs = b0_[bidx] + b1_[bidx] + b2_[bidx] + b3_[bidx];
#pragma unroll
    for (int m = 0; m < 8; ++m) acc[m][n] = (f32x4){bs, bs, bs, bs};
  }

  // staging: one call = 512 thr x 16B = 8 KB = 128 rows x 32 elems (64B/row).
  // Linear LDS dest (base + t*16B); swizzle: LDS chunk c of row r holds global
  // chunk c ^ ((r>>1)&3)  -> 2-way (free) bank aliasing on ds_read (64B rows:
  // bank group depends on row PARITY, so perm must vary with row>>1, not row).
  const int sr   = t >> 2;                              // row 0..127 within call
  const int csrc = (((t & 3) ^ ((t >> 3) & 3)) * 8);    // pre-swizzled src chunk

  auto stA = [&](int kt_, int hf_, int buf_) {
    async_copy16(X + (size_t)(m0 + hf_ * 128 + sr) * KP + kt_ * BK + csrc,
                 smem + buf_ * 16384 + hf_ * 4096 + t * 8);
  };
  auto stB = [&](int kt_, int hf_, int buf_) {
    async_copy16(W + (size_t)(n0 + hf_ * 128 + sr) * KP + kt_ * BK + csrc,
                 smem + buf_ * 16384 + 8192 + hf_ * 4096 + t * 8);
  };

  // frag reads: row = base16 + lr, global chunk kh at LDS chunk kh ^ ((row>>1)&3);
  // base16 is a multiple of 16 -> perm = kh ^ ((lr>>1)&3), lane-constant.
  const int ckr = (kh ^ ((lr >> 1) & 3)) * 8;
  const uint16_t* Abase = smem + (wr * 128 + lr) * 32 + ckr;
  const uint16_t* Bbase = smem + 8192 + (wc * 64 + lr) * 32 + ckr;

  // prologue: tile0 -> buf0, tile1 -> buf1; drain tile0 (4 newest = tile1 stay)
  stA(0, 0, 0); stA(0, 1, 0); stB(0, 0, 0); stB(0, 1, 0);
  stA(1, 0, 1); stA(1, 1, 1); stB(1, 0, 1); stB(1, 1, 1);
  WAITN(4);
  __builtin_amdgcn_s_barrier();
  SB0;

  // groups 0..56 (19 triples), then 57 (last stage), 58 (drain), 59
#pragma unroll 1
  for (int it = 0; it < 19; ++it) {
    const int kt = it * 3;
    GROUP(0, 2, kt,     true, WAITN(4))
    GROUP(1, 0, kt + 1, true, WAITN(4))
    GROUP(2, 1, kt + 2, true, WAITN(4))
  }
  GROUP(0, 2, 57, true,  WAITN(4))
  GROUP(1, 0, 58, false, WAITN(0))
  GROUP(2, 1, 59, false, (void)0)

  // ---- fused epilogue: 4 rounds of 64 rows through pre[64][256] (64 KiB,
  //      bufs 0/1 only -> disjoint from group 59's buf2).
  //      col XOR'd by writer's kh<<4 -> 2-way (free) aliasing both sides. ----
  float* pre  = (float*)smem;
  float* outh = out;
  float* outc = out + (size_t)B_DIM * H_DIM;
  const int eu = lane;
#pragma unroll 1
  for (int ph = 0; ph < 4; ++ph) {
    if (wr == (ph >> 1)) {
      const int mb = (ph & 1) * 4;
#pragma unroll
      for (int mi = 0; mi < 4; ++mi)
#pragma unroll
        for (int n = 0; n < 4; ++n) {
          int rr  = mi * 16 + kh * 4;
          int col = wc * 64 + ((n ^ kh) << 4) + lr;
#pragma unroll
          for (int j = 0; j < 4; ++j)
            pre[(rr + j) * 256 + col] = acc[mb + mi][n][j];
        }
    }
    __syncthreads();
#pragma unroll 1
    for (int q = 0; q < 8; ++q) {
      int rr  = wid * 8 + q;
      int ec  = eu ^ ((rr & 12) << 2);
      float pi = pre[rr * 256 + ec];
      float pf = pre[rr * 256 + 64 + ec];
      float po = pre[rr * 256 + 128 + ec];
      float pg = pre[rr * 256 + 192 + ec];
      size_t o = (size_t)(m0 + ph * 64 + rr) * H_DIM + by * 64 + eu;
      float cp = c_prev[o];
      float iv = 1.f / (1.f + __expf(-pi));
      float fv = 1.f / (1.f + __expf(-pf));
      float ov = 1.f / (1.f + __expf(-po));
      float gv = fast_tanh(pg);
      float ct = fv * cp + iv * gv;
      float ht = ov * fast_tanh(ct);
      outh[o] = ht;
      outc[o] = ct;
    }
    __syncthreads();
  }
}

extern "C" void kernel_launch(void* const* d_in, const int* in_sizes, int n_in,
                              void* d_out, int out_size, void* d_ws, size_t ws_size,
                              hipStream_t stream) {
  const float* h_prev = (const float*)d_in[0];
  const float* c_prev = (const float*)d_in[1];
  const float* emb    = (const float*)d_in[2];
  const float* ctx    = (const float*)d_in[3];
  const float* Wh     = (const float*)d_in[4];
  const float* Wx     = (const float*)d_in[5];
  const float* Wa     = (const float*)d_in[6];
  const float* bl     = (const float*)d_in[7];
  const float* bl2    = (const float*)d_in[8];
  const float* bl3    = (const float*)d_in[9];
  const float* bp     = (const float*)d_in[10];

  uint16_t* X = (uint16_t*)d_ws;                                   // 31.5 MB
  uint16_t* W = (uint16_t*)((char*)d_ws + (size_t)B_DIM * KP * 2); // 15.7 MB
  float* out = (float*)d_out;

  {
    int total = B_DIM * (KP / 8);
    pack_x_kernel<<<(total + 255) / 256, 256, 0, stream>>>(h_prev, emb, ctx, X);
  }
  {
    int total = 4096 * (KP / 8);
    pack_w_kernel<<<(total + 255) / 256, 256, 0, stream>>>(Wh, Wx, Wa, W);
  }
  dim3 grid(B_DIM / 256, 4096 / 256);   // (32, 16)
  lstm_fused_kernel<<<grid, 512, 0, stream>>>(X, W, c_prev, bl, bl2, bl3, bp, out);
}

// Round 5
// 262.240 us; speedup vs baseline: 1.0710x; 1.0052x over previous
//
#include <hip/hip_runtime.h>
#include <stdint.h>

#define B_DIM 8192
#define H_DIM 1024
#define E_DIM 300
#define A_DIM 512
#define KP    1920   // 1024 + 320(pad 300) + 512 + 64 zero-pad = 60*32
#define KE0   1024
#define KA0   1344
#define KA1   1856
#define BK    32
#define NT    60     // K tiles of 32

typedef __bf16 bf16;
typedef bf16  bf16x8 __attribute__((ext_vector_type(8)));
typedef float f32x4  __attribute__((ext_vector_type(4)));

__device__ __forceinline__ uint16_t f2bf(float f) {
  uint32_t u = __float_as_uint(f);
  u += 0x7fff + ((u >> 16) & 1);   // round-to-nearest-even
  return (uint16_t)(u >> 16);
}

// ---- pack X = [B][KP] bf16 : [h | emb | pad | ctx | pad] ----
__global__ void pack_x_kernel(const float* __restrict__ h,
                              const float* __restrict__ e,
                              const float* __restrict__ a,
                              uint16_t* __restrict__ X) {
  int idx = blockIdx.x * blockDim.x + threadIdx.x;
  const int gpr = KP / 8;
  if (idx >= B_DIM * gpr) return;
  int row  = idx / gpr;
  int col0 = (idx % gpr) * 8;
  __align__(16) uint16_t v[8];
#pragma unroll
  for (int j = 0; j < 8; ++j) {
    int c = col0 + j;
    float x;
    if (c < KE0) x = h[(size_t)row * H_DIM + c];
    else if (c < KA0) {
      int ce = c - KE0;
      x = (ce < E_DIM) ? e[(size_t)row * E_DIM + ce] : 0.f;
    } else if (c < KA1) x = a[(size_t)row * A_DIM + (c - KA0)];
    else x = 0.f;
    v[j] = f2bf(x);
  }
  *(uint4*)(X + (size_t)row * KP + col0) = *(const uint4*)v;
}

// ---- pack W = [4096][KP] bf16, gate-interleaved at 64-unit granularity ----
__global__ void pack_w_kernel(const float* __restrict__ Wh,
                              const float* __restrict__ Wx,
                              const float* __restrict__ Wa,
                              uint16_t* __restrict__ W) {
  int idx = blockIdx.x * blockDim.x + threadIdx.x;
  const int gpr = KP / 8;
  if (idx >= 4096 * gpr) return;
  int pr   = idx / gpr;
  int col0 = (idx % gpr) * 8;
  int ub = pr >> 8, g = (pr >> 6) & 3, ui = pr & 63;
  size_t srow = (size_t)(g * H_DIM + ub * 64 + ui);
  __align__(16) uint16_t v[8];
#pragma unroll
  for (int j = 0; j < 8; ++j) {
    int c = col0 + j;
    float x;
    if (c < KE0) x = Wh[srow * H_DIM + c];
    else if (c < KA0) {
      int ce = c - KE0;
      x = (ce < E_DIM) ? Wx[srow * E_DIM + ce] : 0.f;
    } else if (c < KA1) x = Wa[srow * A_DIM + (c - KA0)];
    else x = 0.f;
    v[j] = f2bf(x);
  }
  *(uint4*)(W + (size_t)pr * KP + col0) = *(const uint4*)v;
}

__device__ __forceinline__ void async_copy16(const void* g, void* l) {
  __builtin_amdgcn_global_load_lds(
      (__attribute__((address_space(1))) void*)g,
      (__attribute__((address_space(3))) void*)l, 16, 0, 0);
}

__device__ __forceinline__ float fast_tanh(float x) {
  float ax = fabsf(x);
  float e  = __expf(2.f * ax);
  float r  = 1.f - 2.f / (e + 1.f);
  return copysignf(r, x);
}

#define WAITN(n) asm volatile("s_waitcnt vmcnt(" #n ")" ::: "memory")
#define SB0 __builtin_amdgcn_sched_barrier(0)

#define MH(C, M)                                                                                   \
  acc[M][0] = __builtin_amdgcn_mfma_f32_16x16x32_bf16(Afr[C][M], Bfr[C][0], acc[M][0], 0, 0, 0);   \
  acc[M][1] = __builtin_amdgcn_mfma_f32_16x16x32_bf16(Afr[C][M], Bfr[C][1], acc[M][1], 0, 0, 0);   \
  acc[M][2] = __builtin_amdgcn_mfma_f32_16x16x32_bf16(Afr[C][M], Bfr[C][2], acc[M][2], 0, 0, 0);   \
  acc[M][3] = __builtin_amdgcn_mfma_f32_16x16x32_bf16(Afr[C][M], Bfr[C][3], acc[M][3], 0, 0, 0);

// Group g (K-tile g): stage tile g+2 (WAR-safe: buf (g+2)&3 held tile g-2,
// whose reads finished before barrier g-1), drain tile g+1 (vmcnt(4)),
// barrier publishes it, ISSUE tile g+1's frag reads into regset NXT, then
// run tile g's 32 MFMA from regset CUR under lgkmcnt(8) — the 12 new reads
// stay in flight beneath the MFMAs (LDS latency/BW hidden under matrix pipe).
// Second-half A reads issued between MFMA halves to cap live VGPRs.
// Compiler auto-waits guarantee all register deps; asm waits only tighten.
#define GROUPG(G, CUR, NXT, DOSTAGE, WN_CODE, DOREAD)                                 \
  {                                                                                   \
    if (DOSTAGE) {                                                                    \
      uint16_t* fb = smem + (((G) + 2) & 3) * 16384;                                  \
      stA((G) + 2, fb); stB((G) + 2, fb);                                             \
    }                                                                                 \
    WN_CODE;                                                                          \
    __builtin_amdgcn_s_barrier();                                                     \
    SB0;                                                                              \
    if (DOREAD) {                                                                     \
      const uint16_t* rA = smem + (((G) + 1) & 3) * 16384 + aoff;                     \
      const uint16_t* rB = smem + (((G) + 1) & 3) * 16384 + boff;                     \
      Bfr[NXT][0] = *(const bf16x8*)(rB);                                             \
      Bfr[NXT][1] = *(const bf16x8*)(rB + 512);                                       \
      Bfr[NXT][2] = *(const bf16x8*)(rB + 1024);                                      \
      Bfr[NXT][3] = *(const bf16x8*)(rB + 1536);                                      \
      Afr[NXT][0] = *(const bf16x8*)(rA);                                             \
      Afr[NXT][1] = *(const bf16x8*)(rA + 512);                                       \
      Afr[NXT][2] = *(const bf16x8*)(rA + 1024);                                      \
      Afr[NXT][3] = *(const bf16x8*)(rA + 1536);                                      \
    }                                                                                 \
    asm volatile("s_waitcnt lgkmcnt(8)" ::: "memory");                                \
    SB0;                                                                              \
    MH(CUR, 0) MH(CUR, 1) MH(CUR, 2) MH(CUR, 3)                                       \
    if (DOREAD) {                                                                     \
      const uint16_t* rA2 = smem + (((G) + 1) & 3) * 16384 + aoff;                    \
      Afr[NXT][4] = *(const bf16x8*)(rA2 + 2048);                                     \
      Afr[NXT][5] = *(const bf16x8*)(rA2 + 2560);                                     \
      Afr[NXT][6] = *(const bf16x8*)(rA2 + 3072);                                     \
      Afr[NXT][7] = *(const bf16x8*)(rA2 + 3584);                                     \
    }                                                                                 \
    SB0;                                                                              \
    MH(CUR, 4) MH(CUR, 5) MH(CUR, 6) MH(CUR, 7)                                       \
  }

// ---- fused GEMM + gates: 256x256 tile, 8 waves (2Mx4N), BK=32,
//      4-buffer LDS rotation, 1 barrier + 1 counted vmcnt per K-tile,
//      one-tile-ahead register prefetch (double frag regsets). ----
__global__ __launch_bounds__(512, 2) void lstm_fused_kernel(
    const uint16_t* __restrict__ X, const uint16_t* __restrict__ W,
    const float* __restrict__ c_prev,
    const float* __restrict__ b0_, const float* __restrict__ b1_,
    const float* __restrict__ b2_, const float* __restrict__ b3_,
    float* __restrict__ out) {
  __shared__ __align__(16) uint16_t smem[4 * 16384];  // 128 KiB: 4 x (A16K|B16K)

  const int t    = threadIdx.x;
  const int lane = t & 63;
  const int wid  = t >> 6;
  const int wr   = wid >> 2;            // 0..1 : row half (128 rows each)
  const int wc   = wid & 3;             // 0..3 : gate / 64-col block
  const int lr   = lane & 15;
  const int kh   = lane >> 4;
  const int m0   = blockIdx.x * 256;
  const int by   = blockIdx.y;
  const int n0   = by * 256;            // packed-W row base

  // bias folded into accumulator init
  f32x4 acc[8][4];
#pragma unroll
  for (int n = 0; n < 4; ++n) {
    int bidx = wc * H_DIM + by * 64 + n * 16 + lr;
    float bs = b0_[bidx] + b1_[bidx] + b2_[bidx] + b3_[bidx];
#pragma unroll
    for (int m = 0; m < 8; ++m) acc[m][n] = (f32x4){bs, bs, bs, bs};
  }

  // staging: one stX call = 2 x (512 thr x 16B) = two 128-row x 64B panels.
  // Linear LDS dest (base + t*16B); swizzle: LDS chunk c of row r holds global
  // chunk c ^ ((r>>1)&3) -> 2-way (free) aliasing on ds_read (64B rows).
  const int sr   = t >> 2;                              // row 0..127 within panel
  const int csrc = (((t & 3) ^ ((t >> 3) & 3)) * 8);    // pre-swizzled src chunk

  auto stA = [&](int kt_, uint16_t* fb_) {
    async_copy16(X + (size_t)(m0 + sr) * KP + kt_ * BK + csrc,       fb_ + t * 8);
    async_copy16(X + (size_t)(m0 + 128 + sr) * KP + kt_ * BK + csrc, fb_ + 4096 + t * 8);
  };
  auto stB = [&](int kt_, uint16_t* fb_) {
    async_copy16(W + (size_t)(n0 + sr) * KP + kt_ * BK + csrc,       fb_ + 8192 + t * 8);
    async_copy16(W + (size_t)(n0 + 128 + sr) * KP + kt_ * BK + csrc, fb_ + 12288 + t * 8);
  };

  // frag reads: row = base16 + lr, global chunk kh at LDS chunk kh ^ ((row>>1)&3);
  // base16 multiple of 16 -> perm = kh ^ ((lr>>1)&3), lane-constant.
  const int ckr  = (kh ^ ((lr >> 1) & 3)) * 8;
  const int aoff = (wr * 128 + lr) * 32 + ckr;
  const int boff = 8192 + (wc * 64 + lr) * 32 + ckr;

  bf16x8 Afr[2][8];
  bf16x8 Bfr[2][4];

  // drain bias loads so the vmcnt ledger below counts only staging
  WAITN(0); SB0;

  // prologue: tile0 -> buf0, tile1 -> buf1; drain tile0; read tile0 -> set0
  stA(0, smem); stB(0, smem);
  stA(1, smem + 16384); stB(1, smem + 16384);
  WAITN(4);
  __builtin_amdgcn_s_barrier();
  SB0;
  {
    const uint16_t* rA = smem + aoff;
    const uint16_t* rB = smem + boff;
    Bfr[0][0] = *(const bf16x8*)(rB);
    Bfr[0][1] = *(const bf16x8*)(rB + 512);
    Bfr[0][2] = *(const bf16x8*)(rB + 1024);
    Bfr[0][3] = *(const bf16x8*)(rB + 1536);
    Afr[0][0] = *(const bf16x8*)(rA);
    Afr[0][1] = *(const bf16x8*)(rA + 512);
    Afr[0][2] = *(const bf16x8*)(rA + 1024);
    Afr[0][3] = *(const bf16x8*)(rA + 1536);
    Afr[0][4] = *(const bf16x8*)(rA + 2048);
    Afr[0][5] = *(const bf16x8*)(rA + 2560);
    Afr[0][6] = *(const bf16x8*)(rA + 3072);
    Afr[0][7] = *(const bf16x8*)(rA + 3584);
  }

  // groups 0..55 in a 2-group-unrolled loop (all stage, uniform vmcnt(4)),
  // then explicit tail groups 56..59.
#pragma unroll 1
  for (int it = 0; it < 28; ++it) {
    const int g = 2 * it;
    GROUPG(g,     0, 1, true, WAITN(4), true)
    GROUPG(g + 1, 1, 0, true, WAITN(4), true)
  }
  GROUPG(56, 0, 1, true,  WAITN(4), true)
  GROUPG(57, 1, 0, true,  WAITN(4), true)
  GROUPG(58, 0, 1, false, WAITN(0), true)
  GROUPG(59, 1, 0, false, (void)0,  false)

  // ---- fused epilogue: 4 rounds of 64 rows through pre[64][256] (64 KiB =
  //      bufs 0/1; tiles 58/59 lived in bufs 2/3, all reads of bufs 0/1
  //      completed before barrier of group 58).
  //      col XOR'd by writer's kh<<4 -> 2-way (free) aliasing both sides. ----
  float* pre  = (float*)smem;
  float* outh = out;
  float* outc = out + (size_t)B_DIM * H_DIM;
  const int eu = lane;
#pragma unroll 1
  for (int ph = 0; ph < 4; ++ph) {
    if (wr == (ph >> 1)) {
      const int mb = (ph & 1) * 4;
#pragma unroll
      for (int mi = 0; mi < 4; ++mi)
#pragma unroll
        for (int n = 0; n < 4; ++n) {
          int rr  = mi * 16 + kh * 4;
          int col = wc * 64 + ((n ^ kh) << 4) + lr;
#pragma unroll
          for (int j = 0; j < 4; ++j)
            pre[(rr + j) * 256 + col] = acc[mb + mi][n][j];
        }
    }
    __syncthreads();
#pragma unroll 1
    for (int q = 0; q < 8; ++q) {
      int rr  = wid * 8 + q;
      int ec  = eu ^ ((rr & 12) << 2);
      float pi = pre[rr * 256 + ec];
      float pf = pre[rr * 256 + 64 + ec];
      float po = pre[rr * 256 + 128 + ec];
      float pg = pre[rr * 256 + 192 + ec];
      size_t o = (size_t)(m0 + ph * 64 + rr) * H_DIM + by * 64 + eu;
      float cp = c_prev[o];
      float iv = 1.f / (1.f + __expf(-pi));
      float fv = 1.f / (1.f + __expf(-pf));
      float ov = 1.f / (1.f + __expf(-po));
      float gv = fast_tanh(pg);
      float ct = fv * cp + iv * gv;
      float ht = ov * fast_tanh(ct);
      outh[o] = ht;
      outc[o] = ct;
    }
    __syncthreads();
  }
}

extern "C" void kernel_launch(void* const* d_in, const int* in_sizes, int n_in,
                              void* d_out, int out_size, void* d_ws, size_t ws_size,
                              hipStream_t stream) {
  const float* h_prev = (const float*)d_in[0];
  const float* c_prev = (const float*)d_in[1];
  const float* emb    = (const float*)d_in[2];
  const float* ctx    = (const float*)d_in[3];
  const float* Wh     = (const float*)d_in[4];
  const float* Wx     = (const float*)d_in[5];
  const float* Wa     = (const float*)d_in[6];
  const float* bl     = (const float*)d_in[7];
  const float* bl2    = (const float*)d_in[8];
  const float* bl3    = (const float*)d_in[9];
  const float* bp     = (const float*)d_in[10];

  uint16_t* X = (uint16_t*)d_ws;                                   // 31.5 MB
  uint16_t* W = (uint16_t*)((char*)d_ws + (size_t)B_DIM * KP * 2); // 15.7 MB
  float* out = (float*)d_out;

  {
    int total = B_DIM * (KP / 8);
    pack_x_kernel<<<(total + 255) / 256, 256, 0, stream>>>(h_prev, emb, ctx, X);
  }
  {
    int total = 4096 * (KP / 8);
    pack_w_kernel<<<(total + 255) / 256, 256, 0, stream>>>(Wh, Wx, Wa, W);
  }
  dim3 grid(B_DIM / 256, 4096 / 256);   // (32, 16)
  lstm_fused_kernel<<<grid, 512, 0, stream>>>(X, W, c_prev, bl, bl2, bl3, bp, out);
}

// Round 6
// 205.452 us; speedup vs baseline: 1.3670x; 1.2764x over previous
//
#include <hip/hip_runtime.h>
#include <stdint.h>

#define B_DIM 8192
#define H_DIM 1024
#define E_DIM 300
#define A_DIM 512
#define KP    1856   // 1024 + 320(pad of 300) + 512, = 29*64
#define KE0   1024   // start of embedding segment
#define KA0   1344   // start of context segment
#define BM    128
#define BK    64
#define NT    29     // KP/BK

typedef __bf16 bf16;
typedef bf16  bf16x8 __attribute__((ext_vector_type(8)));
typedef float f32x4  __attribute__((ext_vector_type(4)));

__device__ __forceinline__ uint16_t f2bf(float f) {
  uint32_t u = __float_as_uint(f);
  u += 0x7fff + ((u >> 16) & 1);   // round-to-nearest-even
  return (uint16_t)(u >> 16);
}

// ---- merged pack: X = [B][KP] bf16 [h|emb|pad|ctx], W = [4096][KP] bf16
//      [Wh|Wx|pad|Wa] (row r = g*1024+o) — one launch, overlapped traffic ----
__global__ void pack_xw_kernel(const float* __restrict__ h,
                               const float* __restrict__ e,
                               const float* __restrict__ a,
                               const float* __restrict__ Wh,
                               const float* __restrict__ Wx,
                               const float* __restrict__ Wa,
                               uint16_t* __restrict__ X,
                               uint16_t* __restrict__ Wp) {
  int idx = blockIdx.x * blockDim.x + threadIdx.x;
  const int gpr  = KP / 8;                 // 232 groups per row
  const int xtot = B_DIM * gpr;
  __align__(16) uint16_t v[8];
  if (idx < xtot) {
    int row  = idx / gpr;
    int col0 = (idx % gpr) * 8;
#pragma unroll
    for (int j = 0; j < 8; ++j) {
      int c = col0 + j;
      float x;
      if (c < KE0) x = h[(size_t)row * H_DIM + c];
      else if (c < KA0) {
        int ce = c - KE0;
        x = (ce < E_DIM) ? e[(size_t)row * E_DIM + ce] : 0.f;
      } else x = a[(size_t)row * A_DIM + (c - KA0)];
      v[j] = f2bf(x);
    }
    *(uint4*)(X + (size_t)row * KP + col0) = *(const uint4*)v;
  } else {
    idx -= xtot;
    if (idx >= 4096 * gpr) return;
    int row  = idx / gpr;
    int col0 = (idx % gpr) * 8;
#pragma unroll
    for (int j = 0; j < 8; ++j) {
      int c = col0 + j;
      float x;
      if (c < KE0) x = Wh[(size_t)row * 1024 + c];
      else if (c < KA0) {
        int ce = c - KE0;
        x = (ce < E_DIM) ? Wx[(size_t)row * E_DIM + ce] : 0.f;
      } else x = Wa[(size_t)row * A_DIM + (c - KA0)];
      v[j] = f2bf(x);
    }
    *(uint4*)(Wp + (size_t)row * KP + col0) = *(const uint4*)v;
  }
}

__device__ __forceinline__ void async_copy16(const void* g, void* l) {
  __builtin_amdgcn_global_load_lds(
      (__attribute__((address_space(1))) void*)g,
      (__attribute__((address_space(3))) void*)l, 16, 0, 0);
}

__device__ __forceinline__ float fast_tanh(float x) {
  float ax = fabsf(x);
  float e  = __expf(2.f * ax);
  float r  = 1.f - 2.f / (e + 1.f);   // large ax: e->inf -> r->1 (graceful)
  return copysignf(r, x);
}

// ---- fused GEMM + gates: block = 128 rows x (32 units x 4 gates) ----
// r0-proven 2-barrier K-loop (multi-block overlap per m114) + XCD swizzle +
// conflict-free, load-batched epilogue.
__global__ __launch_bounds__(256, 4) void lstm_fused_kernel(
    const uint16_t* __restrict__ X, const uint16_t* __restrict__ W,
    const float* __restrict__ c_prev,
    const float* __restrict__ b0, const float* __restrict__ b1,
    const float* __restrict__ b2, const float* __restrict__ b3,
    float* __restrict__ out) {
  __shared__ __align__(16) uint16_t smem[2 * BM * BK];  // 32 KB
  uint16_t* As = smem;                 // [128][64] swizzled
  uint16_t* Bs = smem + BM * BK;       // [128][64] swizzled
  float*    pre = (float*)smem;        // epilogue reuse: [64][128]

  const int t    = threadIdx.x;
  const int lane = t & 63;
  const int wid  = t >> 6;
  const int wr   = wid >> 1, wc = wid & 1;

  // XCD-aware bijective remap: 2048 blocks = 8 XCDs x 256. Each XCD gets a
  // contiguous chunk = 4 consecutive u-panels (1.9 MB W, L2-resident) x all
  // row tiles -> shorter vmcnt-drain latency (L2 hits instead of HBM).
  const int lid  = blockIdx.y * 64 + blockIdx.x;
  const int lid2 = (lid & 7) * 256 + (lid >> 3);
  const int m0   = (lid2 & 63) * BM;
  const int u0   = (lid2 >> 6) * 32;

  const int lr   = lane & 15;   // fragment row/col
  const int kh   = lane >> 4;   // k-slot 0..3

  f32x4 acc[4][4];
#pragma unroll
  for (int n = 0; n < 4; ++n) {
    int cl   = wc * 64 + n * 16 + lr;          // tile col 0..127
    int bidx = (cl >> 5) * H_DIM + u0 + (cl & 31);
    float bs = b0[bidx] + b1[bidx] + b2[bidx] + b3[bidx];
#pragma unroll
    for (int m = 0; m < 4; ++m) acc[m][n] = (f32x4){bs, bs, bs, bs};
  }

  const int sr   = t >> 3;                         // staging row 0..31 per issue
  const int c8d  = (t & 7) * 8;                    // LDS dest chunk (linear)
  const int csrc = ((t & 7) ^ (sr & 7)) * 8;       // pre-swizzled global chunk

  for (int kt = 0; kt < NT; ++kt) {
    const int k0 = kt * BK;
#pragma unroll
    for (int q = 0; q < 4; ++q) {
      async_copy16(X + (size_t)(m0 + q * 32 + sr) * KP + k0 + csrc,
                   As + (q * 32 + sr) * BK + c8d);
      // gate = q; B-row = gate*1024 + u0 + sr
      async_copy16(W + (size_t)(q * 1024 + u0 + sr) * KP + k0 + csrc,
                   Bs + (q * 32 + sr) * BK + c8d);
    }
    asm volatile("s_waitcnt vmcnt(0)" ::: "memory");
    __syncthreads();
#pragma unroll
    for (int kk = 0; kk < 2; ++kk) {
      bf16x8 af[4], bfr[4];
#pragma unroll
      for (int m = 0; m < 4; ++m) {
        int row = wr * 64 + m * 16 + lr;
        af[m] = *(const bf16x8*)(As + row * BK + (((kk * 4 + kh) ^ (row & 7)) * 8));
      }
#pragma unroll
      for (int n = 0; n < 4; ++n) {
        int row = wc * 64 + n * 16 + lr;
        bfr[n] = *(const bf16x8*)(Bs + row * BK + (((kk * 4 + kh) ^ (row & 7)) * 8));
      }
#pragma unroll
      for (int m = 0; m < 4; ++m)
#pragma unroll
        for (int n = 0; n < 4; ++n)
          acc[m][n] = __builtin_amdgcn_mfma_f32_16x16x32_bf16(af[m], bfr[n], acc[m][n], 0, 0, 0);
    }
    __syncthreads();
  }

  // ---- fused epilogue: two 64-row phases through 32 KB LDS.
  //      pre[] cols swizzled: logical col c at physical (c&~15)|((c&15)^(kh<<2))
  //      where kh=(row>>2)&3 -> stores AND loads 2-way (free) bank aliasing.
  //      c_prev batched ahead of the math to hide HBM latency. ----
  float* outh = out;
  float* outc = out + (size_t)B_DIM * H_DIM;
  const int eu = t & 31;
  const int rb = (t >> 5) * 8;
#pragma unroll 1
  for (int phase = 0; phase < 2; ++phase) {
    if (wr == phase) {
#pragma unroll
      for (int m = 0; m < 4; ++m)
#pragma unroll
        for (int n = 0; n < 4; ++n) {
          int colw = wc * 64 + n * 16 + (lr ^ (kh << 2));
#pragma unroll
          for (int j = 0; j < 4; ++j)
            pre[(m * 16 + kh * 4 + j) * 128 + colw] = acc[m][n][j];
        }
    }
    __syncthreads();
    size_t ob = (size_t)(m0 + phase * 64 + rb) * H_DIM + u0 + eu;
    float cp[8];
#pragma unroll
    for (int q = 0; q < 8; ++q) cp[q] = c_prev[ob + (size_t)q * H_DIM];
#pragma unroll
    for (int q = 0; q < 8; ++q) {
      int r    = rb + q;
      int ecol = (eu & 16) | ((eu & 15) ^ (((r >> 2) & 3) << 2));
      float pi = pre[r * 128 +      ecol];
      float pf = pre[r * 128 + 32 + ecol];
      float po = pre[r * 128 + 64 + ecol];
      float pg = pre[r * 128 + 96 + ecol];
      float iv = 1.f / (1.f + __expf(-pi));
      float fv = 1.f / (1.f + __expf(-pf));
      float ov = 1.f / (1.f + __expf(-po));
      float gv = fast_tanh(pg);
      float ct = fv * cp[q] + iv * gv;
      float ht = ov * fast_tanh(ct);
      size_t o = ob + (size_t)q * H_DIM;
      outh[o] = ht;
      outc[o] = ct;
    }
    __syncthreads();
  }
}

extern "C" void kernel_launch(void* const* d_in, const int* in_sizes, int n_in,
                              void* d_out, int out_size, void* d_ws, size_t ws_size,
                              hipStream_t stream) {
  const float* h_prev = (const float*)d_in[0];
  const float* c_prev = (const float*)d_in[1];
  const float* emb    = (const float*)d_in[2];
  const float* ctx    = (const float*)d_in[3];
  const float* Wh     = (const float*)d_in[4];
  const float* Wx     = (const float*)d_in[5];
  const float* Wa     = (const float*)d_in[6];
  const float* bl     = (const float*)d_in[7];
  const float* bl2    = (const float*)d_in[8];
  const float* bl3    = (const float*)d_in[9];
  const float* bp     = (const float*)d_in[10];

  uint16_t* X = (uint16_t*)d_ws;                                   // 30.4 MB
  uint16_t* W = (uint16_t*)((char*)d_ws + (size_t)B_DIM * KP * 2); // 15.2 MB
  float* out = (float*)d_out;

  {
    int total = (B_DIM + 4096) * (KP / 8);
    pack_xw_kernel<<<(total + 255) / 256, 256, 0, stream>>>(h_prev, emb, ctx,
                                                            Wh, Wx, Wa, X, W);
  }
  dim3 grid(B_DIM / BM, H_DIM / 32);
  lstm_fused_kernel<<<grid, 256, 0, stream>>>(X, W, c_prev, bl, bl2, bl3, bp, out);
}

// Round 7
// 174.645 us; speedup vs baseline: 1.6082x; 1.1764x over previous
//
#include <hip/hip_runtime.h>
#include <stdint.h>

#define B_DIM 8192
#define H_DIM 1024
#define E_DIM 300
#define A_DIM 512
#define KP    1856   // 1024 + 320(pad of 300) + 512, = 29*64
#define KE0   1024   // start of embedding segment
#define KA0   1344   // start of context segment
#define BM    128
#define BK    64
#define NT    29     // KP/BK

typedef __bf16 bf16;
typedef bf16  bf16x8 __attribute__((ext_vector_type(8)));
typedef float f32x4  __attribute__((ext_vector_type(4)));

__device__ __forceinline__ uint16_t f2bf(float f) {
  uint32_t u = __float_as_uint(f);
  u += 0x7fff + ((u >> 16) & 1);   // round-to-nearest-even
  return (uint16_t)(u >> 16);
}

// ---- pack X = [B][KP] bf16 : [h | emb | pad | ctx] ----
__global__ void pack_x_kernel(const float* __restrict__ h,
                              const float* __restrict__ e,
                              const float* __restrict__ a,
                              uint16_t* __restrict__ X) {
  int idx = blockIdx.x * blockDim.x + threadIdx.x;
  const int gpr = KP / 8;                 // 232 groups per row
  if (idx >= B_DIM * gpr) return;
  int row  = idx / gpr;
  int col0 = (idx % gpr) * 8;
  __align__(16) uint16_t v[8];
#pragma unroll
  for (int j = 0; j < 8; ++j) {
    int c = col0 + j;
    float x;
    if (c < KE0) x = h[(size_t)row * H_DIM + c];
    else if (c < KA0) {
      int ce = c - KE0;
      x = (ce < E_DIM) ? e[(size_t)row * E_DIM + ce] : 0.f;
    } else x = a[(size_t)row * A_DIM + (c - KA0)];
    v[j] = f2bf(x);
  }
  *(uint4*)(X + (size_t)row * KP + col0) = *(const uint4*)v;
}

// ---- pack W = [4096][KP] bf16, row r = g*1024+o : [Wh | Wx | pad | Wa] ----
__global__ void pack_w_kernel(const float* __restrict__ Wh,
                              const float* __restrict__ Wx,
                              const float* __restrict__ Wa,
                              uint16_t* __restrict__ W) {
  int idx = blockIdx.x * blockDim.x + threadIdx.x;
  const int gpr = KP / 8;
  if (idx >= 4096 * gpr) return;
  int row  = idx / gpr;
  int col0 = (idx % gpr) * 8;
  __align__(16) uint16_t v[8];
#pragma unroll
  for (int j = 0; j < 8; ++j) {
    int c = col0 + j;
    float x;
    if (c < KE0) x = Wh[(size_t)row * 1024 + c];
    else if (c < KA0) {
      int ce = c - KE0;
      x = (ce < E_DIM) ? Wx[(size_t)row * E_DIM + ce] : 0.f;
    } else x = Wa[(size_t)row * A_DIM + (c - KA0)];
    v[j] = f2bf(x);
  }
  *(uint4*)(W + (size_t)row * KP + col0) = *(const uint4*)v;
}

__device__ __forceinline__ void async_copy16(const void* g, void* l) {
  __builtin_amdgcn_global_load_lds(
      (__attribute__((address_space(1))) void*)g,
      (__attribute__((address_space(3))) void*)l, 16, 0, 0);
}

__device__ __forceinline__ float fast_tanh(float x) {
  float ax = fabsf(x);
  float e  = __expf(2.f * ax);
  float r  = 1.f - 2.f / (e + 1.f);   // large ax: e->inf -> r->1 (graceful)
  return copysignf(r, x);
}

// ---- fused GEMM + gates: block = 128 rows x (32 units x 4 gates) ----
// r0-proven 2-barrier K-loop (multi-block overlap per m114), natural block
// order (L3-friendly), conflict-free load-batched epilogue.
__global__ __launch_bounds__(256, 4) void lstm_fused_kernel(
    const uint16_t* __restrict__ X, const uint16_t* __restrict__ W,
    const float* __restrict__ c_prev,
    const float* __restrict__ b0, const float* __restrict__ b1,
    const float* __restrict__ b2, const float* __restrict__ b3,
    float* __restrict__ out) {
  __shared__ __align__(16) uint16_t smem[2 * BM * BK];  // 32 KB
  uint16_t* As = smem;                 // [128][64] swizzled
  uint16_t* Bs = smem + BM * BK;       // [128][64] swizzled
  float*    pre = (float*)smem;        // epilogue reuse: [64][128]

  const int t    = threadIdx.x;
  const int lane = t & 63;
  const int wid  = t >> 6;
  const int wr   = wid >> 1, wc = wid & 1;
  const int m0   = blockIdx.x * BM;
  const int u0   = blockIdx.y * 32;
  const int lr   = lane & 15;   // fragment row/col
  const int kh   = lane >> 4;   // k-slot 0..3

  f32x4 acc[4][4];
#pragma unroll
  for (int n = 0; n < 4; ++n) {
    int cl   = wc * 64 + n * 16 + lr;          // tile col 0..127
    int bidx = (cl >> 5) * H_DIM + u0 + (cl & 31);
    float bs = b0[bidx] + b1[bidx] + b2[bidx] + b3[bidx];
#pragma unroll
    for (int m = 0; m < 4; ++m) acc[m][n] = (f32x4){bs, bs, bs, bs};
  }

  const int sr   = t >> 3;                         // staging row 0..31 per issue
  const int c8d  = (t & 7) * 8;                    // LDS dest chunk (linear)
  const int csrc = ((t & 7) ^ (sr & 7)) * 8;       // pre-swizzled global chunk

  for (int kt = 0; kt < NT; ++kt) {
    const int k0 = kt * BK;
#pragma unroll
    for (int q = 0; q < 4; ++q) {
      async_copy16(X + (size_t)(m0 + q * 32 + sr) * KP + k0 + csrc,
                   As + (q * 32 + sr) * BK + c8d);
      // gate = q; B-row = gate*1024 + u0 + sr
      async_copy16(W + (size_t)(q * 1024 + u0 + sr) * KP + k0 + csrc,
                   Bs + (q * 32 + sr) * BK + c8d);
    }
    asm volatile("s_waitcnt vmcnt(0)" ::: "memory");
    __syncthreads();
#pragma unroll
    for (int kk = 0; kk < 2; ++kk) {
      bf16x8 af[4], bfr[4];
#pragma unroll
      for (int m = 0; m < 4; ++m) {
        int row = wr * 64 + m * 16 + lr;
        af[m] = *(const bf16x8*)(As + row * BK + (((kk * 4 + kh) ^ (row & 7)) * 8));
      }
#pragma unroll
      for (int n = 0; n < 4; ++n) {
        int row = wc * 64 + n * 16 + lr;
        bfr[n] = *(const bf16x8*)(Bs + row * BK + (((kk * 4 + kh) ^ (row & 7)) * 8));
      }
#pragma unroll
      for (int m = 0; m < 4; ++m)
#pragma unroll
        for (int n = 0; n < 4; ++n)
          acc[m][n] = __builtin_amdgcn_mfma_f32_16x16x32_bf16(af[m], bfr[n], acc[m][n], 0, 0, 0);
    }
    __syncthreads();
  }

  // ---- fused epilogue: two 64-row phases through 32 KB LDS.
  //      pre[] col ROTATION swizzle: logical col c of row r stored at
  //      phys = (c&96) | (((c&31) + 8*((r>>2)&3)) & 31).
  //      Store banks: (16n + lr + 8*kh) mod 32 -> exactly 2 lanes/bank (free).
  //      Load banks:  (eu + 8*k(r)) mod 32, halves offset by 16 -> 2-way (free).
  //      (r0/r6 had 4-way on stores: SQ_LDS_BANK_CONFLICT = 2^20 exactly.)
  //      c_prev batched ahead of the dependent math chain. ----
  float* outh = out;
  float* outc = out + (size_t)B_DIM * H_DIM;
  const int eu = t & 31;
  const int rb = (t >> 5) * 8;
#pragma unroll 1
  for (int phase = 0; phase < 2; ++phase) {
    if (wr == phase) {
#pragma unroll
      for (int m = 0; m < 4; ++m)
#pragma unroll
        for (int n = 0; n < 4; ++n) {
          int col  = wc * 64 + n * 16 + lr;
          int colw = (col & 96) | (((col & 31) + 8 * kh) & 31);
#pragma unroll
          for (int j = 0; j < 4; ++j)
            pre[(m * 16 + kh * 4 + j) * 128 + colw] = acc[m][n][j];
        }
    }
    __syncthreads();
    size_t ob = (size_t)(m0 + phase * 64 + rb) * H_DIM + u0 + eu;
    float cp[8];
#pragma unroll
    for (int q = 0; q < 8; ++q) cp[q] = c_prev[ob + (size_t)q * H_DIM];
#pragma unroll
    for (int q = 0; q < 8; ++q) {
      int r  = rb + q;
      int rk = (r >> 2) & 3;
      int e0 = (eu + 8 * rk) & 31;     // phys within 32-group (goff adds 0 mod 32)
      float pi = pre[r * 128 +      e0];
      float pf = pre[r * 128 + 32 + e0];
      float po = pre[r * 128 + 64 + e0];
      float pg = pre[r * 128 + 96 + e0];
      float iv = 1.f / (1.f + __expf(-pi));
      float fv = 1.f / (1.f + __expf(-pf));
      float ov = 1.f / (1.f + __expf(-po));
      float gv = fast_tanh(pg);
      float ct = fv * cp[q] + iv * gv;
      float ht = ov * fast_tanh(ct);
      size_t o = ob + (size_t)q * H_DIM;
      outh[o] = ht;
      outc[o] = ct;
    }
    __syncthreads();
  }
}

extern "C" void kernel_launch(void* const* d_in, const int* in_sizes, int n_in,
                              void* d_out, int out_size, void* d_ws, size_t ws_size,
                              hipStream_t stream) {
  const float* h_prev = (const float*)d_in[0];
  const float* c_prev = (const float*)d_in[1];
  const float* emb    = (const float*)d_in[2];
  const float* ctx    = (const float*)d_in[3];
  const float* Wh     = (const float*)d_in[4];
  const float* Wx     = (const float*)d_in[5];
  const float* Wa     = (const float*)d_in[6];
  const float* bl     = (const float*)d_in[7];
  const float* bl2    = (const float*)d_in[8];
  const float* bl3    = (const float*)d_in[9];
  const float* bp     = (const float*)d_in[10];

  uint16_t* X = (uint16_t*)d_ws;                                   // 30.4 MB
  uint16_t* W = (uint16_t*)((char*)d_ws + (size_t)B_DIM * KP * 2); // 15.2 MB
  float* out = (float*)d_out;

  {
    int total = B_DIM * (KP / 8);
    pack_x_kernel<<<(total + 255) / 256, 256, 0, stream>>>(h_prev, emb, ctx, X);
  }
  {
    int total = 4096 * (KP / 8);
    pack_w_kernel<<<(total + 255) / 256, 256, 0, stream>>>(Wh, Wx, Wa, W);
  }
  dim3 grid(B_DIM / BM, H_DIM / 32);
  lstm_fused_kernel<<<grid, 256, 0, stream>>>(X, W, c_prev, bl, bl2, bl3, bp, out);
}